// Round 11
// baseline (143.145 us; speedup 1.0000x reference)
//
#include <hip/hip_runtime.h>
#include <math.h>

#define O_CH 32
#define I_CH 3
#define IH 512
#define IW 512
#define OH 510
#define OW 510
#define N_IMG 16
#define WSTRIDE 32       // weight row stride in d_ws
#define BANDS 128        // 4-row bands per image (last band: 2 valid rows)

typedef float v2f __attribute__((ext_vector_type(2)));
typedef float v4f __attribute__((ext_vector_type(4)));

__global__ __launch_bounds__(256) void gabor_weights_kernel(
    const float* __restrict__ freq, const float* __restrict__ theta,
    const float* __restrict__ psi, const float* __restrict__ sigma,
    float* __restrict__ wp) {
  int idx = blockIdx.x * 256 + threadIdx.x;
  if (idx >= O_CH * I_CH * 9) return;
  int o = idx / 27;
  int rem = idx % 27;          // rem = c*9 + kh*3 + kw
  int kh = (rem / 3) % 3;
  int kw = rem % 3;
  // linspace(-ceil(3/2)+1, ceil(3/2), 3) = {-1, 0.5, 2}
  float x = (kw == 0) ? -1.0f : (kw == 1 ? 0.5f : 2.0f);
  float y = (kh == 0) ? -1.0f : (kh == 1 ? 0.5f : 2.0f);
  int pi = o * I_CH + rem / 9; // (O,I) parameter index
  float th = theta[pi], f = freq[pi], p = psi[pi], s = sigma[pi];
  float ct = cosf(th), st = sinf(th);
  float rotx = x * ct + y * st;
  float roty = -x * st + y * ct;
  float se = s + 0.001f;
  float g = expf(-0.5f * (rotx * rotx + roty * roty) / (se * se));
  g *= cosf(f * rotx + p);
  g /= (2.0f * 3.14f * s * s);   // reference uses PI = 3.14 exactly
  wp[o * WSTRIDE + rem] = g;
}

// Packed-FP32 R9 structure with the register window halved for occupancy:
// lane owns 8 px of ONE row (L cols x0..x0+3, R cols +256), v_pk_fma_f32
// pair axis = (L,R) so tap pairs are built once at load with no per-tap
// repacking. Window = 3c x 3r x 6 v2f = 108 VGPR; total ~160 -> 3 waves/SIMD
// EARNED (no min-waves clause — R5/R7: forcing occupancy makes the allocator
// spill the window and re-fetch per o, 7-20x fetch amplification).
// Per o: 7 broadcast ds_read_b128 + 108 pk-FMA + 3-6 stores; weight-read
// fraction ~3% (R8's poison was this ratio at 4px scalar).
// No row clamping anywhere (y<=509 -> y+2<=511). Even rows: 16B dwordx4
// stores; odd rows 8B dwordx2 (L2 merges). XCD chunk swizzle: 2048 blocks,
// q=256 = exactly 2 images per XCD, bands in row order for halo L2 reuse.
__global__ __launch_bounds__(256) void gabor_conv_kernel(
    const float* __restrict__ in, const float* __restrict__ wgp,
    float* __restrict__ out) {
  __shared__ float sW[O_CH][28];   // 27 weights + pad = 7x float4 per o

  const int tid = threadIdx.x;
  for (int i = tid; i < O_CH * 28; i += 256) {
    int o = i / 28, j = i % 28;
    sW[o][j] = (j < 27) ? wgp[o * WSTRIDE + j] : 0.0f;
  }
  __syncthreads();

  const int wave = tid >> 6;   // 0..3 -> row within band
  const int lane = tid & 63;

  // bijective chunked XCD swizzle: 2048 blocks, 256 per XCD (= 2 images)
  const int bid = blockIdx.x;
  const int nid = (bid & 7) * 256 + (bid >> 3);
  const int n    = nid >> 7;           // image 0..15
  const int band = nid & 127;          // 4-row band 0..127
  const int y    = band * 4 + wave;    // this wave's output row
  if (y >= OH) return;                 // band 127, waves 2/3 only

  const int x0 = lane * 4;             // L px x0..x0+3; R px +256
  const float* inN = in + (size_t)n * (I_CH * IH * IW);

  // Window as (L,R) column pairs: 3 ch x 3 rows x 6 cols = 54 v2f (108 VGPR)
  v2f P[I_CH][3][6];
#pragma unroll
  for (int c = 0; c < I_CH; ++c) {
#pragma unroll
    for (int kh = 0; kh < 3; ++kh) {
      const float* rowp = inN + ((size_t)c * IH + y + kh) * IW;
      v4f LA = *(const v4f*)&rowp[x0];          // cols x0..x0+3 (16B aligned)
      v2f LB = *(const v2f*)&rowp[x0 + 4];      // cols x0+4,x0+5
      v4f RA = *(const v4f*)&rowp[x0 + 256];    // cols x0+256..+259
      int xc = x0 + 260; if (xc > IW - 2) xc = IW - 2;  // lane63: 516 -> 510
      v2f RB = *(const v2f*)&rowp[xc];
      P[c][kh][0] = (v2f){LA.x, RA.x};
      P[c][kh][1] = (v2f){LA.y, RA.y};
      P[c][kh][2] = (v2f){LA.z, RA.z};
      P[c][kh][3] = (v2f){LA.w, RA.w};
      P[c][kh][4] = (v2f){LB.x, RB.x};
      P[c][kh][5] = (v2f){LB.y, RB.y};
    }
  }

  const bool full = (lane != 63);      // lane63 R px 510,511 are OOB
  const bool evenRow = ((y & 1) == 0);
  float* op = out + (((size_t)n * O_CH * OH) + y) * OW + x0;  // o=0, L half

  for (int o = 0; o < O_CH; ++o) {
    float wq[28];
#pragma unroll
    for (int k = 0; k < 7; ++k) {      // 7 broadcast ds_read_b128
      v4f t = *(const v4f*)&sW[o][k * 4];
      wq[4 * k + 0] = t.x; wq[4 * k + 1] = t.y;
      wq[4 * k + 2] = t.z; wq[4 * k + 3] = t.w;
    }
    v2f a[4];
#pragma unroll
    for (int j = 0; j < 4; ++j) a[j] = (v2f){0.f, 0.f};
#pragma unroll
    for (int c = 0; c < I_CH; ++c) {
#pragma unroll
      for (int kh = 0; kh < 3; ++kh) {
#pragma unroll
        for (int kw = 0; kw < 3; ++kw) {
          float w = wq[c * 9 + kh * 3 + kw];
          v2f wv = (v2f){w, w};
#pragma unroll
          for (int j = 0; j < 4; ++j) {    // 4 v_pk_fma_f32 per tap
            a[j] = __builtin_elementwise_fma(P[c][kh][kw + j], wv, a[j]);
          }
        }
      }
    }
    // unpack (L,R) pairs into row-contiguous quads
    v4f L = (v4f){a[0].x, a[1].x, a[2].x, a[3].x};
    v4f R = (v4f){a[0].y, a[1].y, a[2].y, a[3].y};
    if (evenRow) {
      *(v4f*)op = L;                       // 16B aligned
      if (full) *(v4f*)(op + 256) = R;
      else      *(v2f*)(op + 256) = (v2f){R.x, R.y};   // px 508,509
    } else {
      *(v2f*)op       = (v2f){L.x, L.y};   // 8B aligned pieces
      *(v2f*)(op + 2) = (v2f){L.z, L.w};
      *(v2f*)(op + 256) = (v2f){R.x, R.y};
      if (full) *(v2f*)(op + 258) = (v2f){R.z, R.w};
    }
    op += (size_t)(OH * OW);
  }
}

extern "C" void kernel_launch(void* const* d_in, const int* in_sizes, int n_in,
                              void* d_out, int out_size, void* d_ws, size_t ws_size,
                              hipStream_t stream) {
  const float* img   = (const float*)d_in[0];
  const float* freq  = (const float*)d_in[1];
  const float* theta = (const float*)d_in[2];
  const float* psi   = (const float*)d_in[3];
  const float* sigma = (const float*)d_in[4];
  float* outp = (float*)d_out;
  float* wgp = (float*)d_ws;  // 32x32 floats of scratch (Gabor weights)

  gabor_weights_kernel<<<dim3(4), dim3(256), 0, stream>>>(freq, theta, psi, sigma, wgp);

  dim3 grid(N_IMG * BANDS);   // 2048 blocks; block = one 4-row band
  gabor_conv_kernel<<<grid, dim3(256), 0, stream>>>(img, wgp, outp);
}